// Round 9
// baseline (117.486 us; speedup 1.0000x reference)
//
#include <hip/hip_runtime.h>
#include <math.h>

#define BATCH 8
#define NSEQ  4096
#define NWIN  65
#define OUTD  64
#define NB    21
#define NITEMS (BATCH * NWIN * 16)   // 8320 items: bits (bw<<4)|(og<<2)|chunk
#define GRID   768                   // 256 CU x 3 resident
#define IPB    11                    // ceil(8320/768) items per block

typedef __attribute__((ext_vector_type(4))) float f32x4;

// out[b,o,w,s] = a(b,s) * ( const0*coefs[o,0] + sum_{n=1..10} scale*(sin(n*th)*coefs[o,2n-1] + cos(n*th)*coefs[o,2n]) )
// th = (2*pi/78) * c(b,s) * ((w+7) - bshift(b,s))
// R6 inner code exactly (NT stores in compute loop, no rotation). Single new
// variable: each block runs 11 CONSECUTIVE items (chunk varies fastest), so
// item-tail stores drain under the next item's basis compute, and each o-plane
// gets 16KB temporally-adjacent write runs.
__global__ __launch_bounds__(256, 3) void trf_kernel(
    const float* __restrict__ x,        // (8,1,4096)
    const float* __restrict__ conv_w,   // (3,1,2)
    const float* __restrict__ conv_b,   // (3,)
    const float* __restrict__ coefs,    // (64,1,21)
    float* __restrict__ out)            // (8,64,65,4096)
{
    const int tid = threadIdx.x;

    // conv weights: wave-uniform scalar loads (hoisted)
    const float w00 = conv_w[0], w01 = conv_w[1];
    const float w10 = conv_w[2], w11 = conv_w[3];
    const float w20 = conv_w[4], w21 = conv_w[5];
    const float cb0 = conv_b[0], cb1 = conv_b[1], cb2 = conv_b[2];

    const float K      = 0.08055365778435367f;  // 2*pi/78
    const float SCALE  = 0.16012815380508713f;  // 1/sqrt(39)
    const float CONST0 = 0.11322770341445958f;  // 1/(sqrt(2)*sqrt(39))
    const size_t ostride = (size_t)NWIN * NSEQ;

    const int item0 = blockIdx.x * IPB;
    const int item1 = (item0 + IPB < NITEMS) ? item0 + IPB : NITEMS;

    for (int item = item0; item < item1; ++item) {
        const int chunk = item & 3;          // fastest: adjacent 4KB per plane
        const int og    = (item >> 2) & 3;   // then output group
        const int bw    = item >> 4;
        const int w     = bw % NWIN;
        const int b     = bw / NWIN;
        const int s0    = chunk * 1024 + tid * 4;

        const float* xb = x + (size_t)b * NSEQ;
        const f32x4 xq  = *(const f32x4*)(xb + s0);         // 16B aligned
        const float xm0 = (s0 > 0) ? xb[s0 - 1] : 0.0f;     // causal left-pad
        const float wl  = (float)(w + 7);

        f32x4 basis[NB];                                    // 84 VGPRs, static-indexed
#pragma unroll
        for (int p = 0; p < 4; ++p) {
            const float xm = (p == 0) ? xm0 : xq[p - 1];
            const float xc = xq[p];
            const float p0 = fmaf(xm, w00, fmaf(xc, w01, cb0));
            const float p1 = fmaf(xm, w10, fmaf(xc, w11, cb1));
            const float p2 = fmaf(xm, w20, fmaf(xc, w21, cb2));
            const float a  = fabsf(p0);
            const float bs = fminf(fmaxf(p1, -7.0f), 7.0f);
            const float c  = fminf(fmaxf(1.0f + p2, 0.5f), 1.4f);

            const float theta = K * c * (wl - bs);
            float sn, cn;
            __sincosf(theta, &sn, &cn);

            const float fa = a * SCALE;
            basis[0][p] = a * CONST0;
            const float twoc = 2.0f * cn;
            float sp = 0.0f, cp = 1.0f;      // sin(0), cos(0)
            float scur = sn, ccur = cn;      // sin(th), cos(th)
#pragma unroll
            for (int n = 1; n <= 10; ++n) {  // Chebyshev recurrence for sin/cos(n*th)
                basis[2 * n - 1][p] = fa * scur;
                basis[2 * n][p]     = fa * ccur;
                const float snew = fmaf(twoc, scur, -sp);
                const float cnew = fmaf(twoc, ccur, -cp);
                sp = scur; cp = ccur; scur = snew; ccur = cnew;
            }
        }

        // out index: ((b*64 + o)*65 + w)*4096 + s0
        float* op = out + ((size_t)(b * OUTD + og * 16) * NWIN + (size_t)w) * NSEQ + s0;
        const float* cwb = coefs + og * 16 * NB;   // uniform -> s_load batch

#pragma unroll
        for (int j = 0; j < 16; ++j) {
            const float* cw = cwb + j * NB;
            f32x4 a0 = basis[0] * cw[0];
#pragma unroll
            for (int n = 1; n < NB; ++n) {
                const float cs = cw[n];
                const f32x4 cv = {cs, cs, cs, cs};
                a0 = __builtin_elementwise_fma(basis[n], cv, a0);
            }
            // NT store issued inside compute loop (R6 pattern, measured best)
            __builtin_nontemporal_store(a0, (f32x4*)(op + (size_t)j * ostride));
        }
    }
}

extern "C" void kernel_launch(void* const* d_in, const int* in_sizes, int n_in,
                              void* d_out, int out_size, void* d_ws, size_t ws_size,
                              hipStream_t stream) {
    const float* x      = (const float*)d_in[0];
    const float* conv_w = (const float*)d_in[1];
    const float* conv_b = (const float*)d_in[2];
    const float* coefs  = (const float*)d_in[3];
    float* out = (float*)d_out;

    trf_kernel<<<GRID, 256, 0, stream>>>(x, conv_w, conv_b, coefs, out);
}

// Round 10
// 114.597 us; speedup vs baseline: 1.0252x; 1.0252x over previous
//
#include <hip/hip_runtime.h>
#include <math.h>

#define BATCH 8
#define NSEQ  4096
#define NWIN  65
#define OUTD  64
#define NB    21

typedef __attribute__((ext_vector_type(4))) float f32x4;

// out[b,o,w,s] = a(b,s) * ( const0*coefs[o,0] + sum_{n=1..10} scale*(sin(n*th)*coefs[o,2n-1] + cos(n*th)*coefs[o,2n]) )
// th = (2*pi/78) * c(b,s) * ((w+7) - bshift(b,s))
// R6 inner code exactly (NT stores inside compute loop, 16 dedicated accs).
// Single change vs R6: block-index bit remap -> w varies FASTEST across
// consecutive blocks, so temporally-adjacent (staggered) blocks write adjacent
// 4KB pieces of the SAME 16 o-planes -> long contiguous write runs per plane
// (HBM row locality), while keeping natural dispatch stagger.
__global__ __launch_bounds__(256, 3) void trf_kernel(
    const float* __restrict__ x,        // (8,1,4096)
    const float* __restrict__ conv_w,   // (3,1,2)
    const float* __restrict__ conv_b,   // (3,)
    const float* __restrict__ coefs,    // (64,1,21)
    float* __restrict__ out)            // (8,64,65,4096)
{
    const int tid   = threadIdx.x;
    const int blk   = blockIdx.x;
    // blk = ((b*4 + og)*4 + chunk)*65 + w   -> w fastest
    const int w     = blk % NWIN;
    const int rest  = blk / NWIN;
    const int chunk = rest & 3;
    const int og    = (rest >> 2) & 3;
    const int b     = rest >> 4;
    const int s0    = chunk * 1024 + tid * 4;

    // conv weights: wave-uniform scalar loads
    const float w00 = conv_w[0], w01 = conv_w[1];
    const float w10 = conv_w[2], w11 = conv_w[3];
    const float w20 = conv_w[4], w21 = conv_w[5];
    const float cb0 = conv_b[0], cb1 = conv_b[1], cb2 = conv_b[2];

    const float* xb = x + (size_t)b * NSEQ;
    const f32x4 xq  = *(const f32x4*)(xb + s0);            // x[s0..s0+3], 16B aligned
    const float xm0 = (s0 > 0) ? xb[s0 - 1] : 0.0f;        // causal left-pad

    const float K      = 0.08055365778435367f;  // 2*pi/78
    const float SCALE  = 0.16012815380508713f;  // 1/sqrt(39)
    const float CONST0 = 0.11322770341445958f;  // 1/(sqrt(2)*sqrt(39))
    const float wl     = (float)(w + 7);

    f32x4 basis[NB];                                       // 84 VGPRs, static-indexed
#pragma unroll
    for (int p = 0; p < 4; ++p) {
        const float xm = (p == 0) ? xm0 : xq[p - 1];
        const float xc = xq[p];
        const float p0 = fmaf(xm, w00, fmaf(xc, w01, cb0));
        const float p1 = fmaf(xm, w10, fmaf(xc, w11, cb1));
        const float p2 = fmaf(xm, w20, fmaf(xc, w21, cb2));
        const float a  = fabsf(p0);
        const float bs = fminf(fmaxf(p1, -7.0f), 7.0f);
        const float c  = fminf(fmaxf(1.0f + p2, 0.5f), 1.4f);

        const float theta = K * c * (wl - bs);
        float sn, cn;
        __sincosf(theta, &sn, &cn);

        const float fa = a * SCALE;
        basis[0][p] = a * CONST0;
        const float twoc = 2.0f * cn;
        float sp = 0.0f, cp = 1.0f;      // sin(0), cos(0)
        float scur = sn, ccur = cn;      // sin(th), cos(th)
#pragma unroll
        for (int n = 1; n <= 10; ++n) {  // Chebyshev recurrence for sin/cos(n*th)
            basis[2 * n - 1][p] = fa * scur;
            basis[2 * n][p]     = fa * ccur;
            const float snew = fmaf(twoc, scur, -sp);
            const float cnew = fmaf(twoc, ccur, -cp);
            sp = scur; cp = ccur; scur = snew; ccur = cnew;
        }
    }

    // out index: ((b*64 + o)*65 + w)*4096 + s0
    float* op = out + ((size_t)(b * OUTD + og * 16) * NWIN + (size_t)w) * NSEQ + s0;
    const size_t ostride = (size_t)NWIN * NSEQ;

    const float* cwb = coefs + og * 16 * NB;   // uniform -> s_load batch
#pragma unroll
    for (int j = 0; j < 16; ++j) {
        const float* cw = cwb + j * NB;
        f32x4 a0 = basis[0] * cw[0];
#pragma unroll
        for (int n = 1; n < NB; ++n) {
            const float cs = cw[n];
            const f32x4 cv = {cs, cs, cs, cs};
            a0 = __builtin_elementwise_fma(basis[n], cv, a0);
        }
        // NT store issued inside compute loop (R6 pattern, measured best)
        __builtin_nontemporal_store(a0, (f32x4*)(op + (size_t)j * ostride));
    }
}

extern "C" void kernel_launch(void* const* d_in, const int* in_sizes, int n_in,
                              void* d_out, int out_size, void* d_ws, size_t ws_size,
                              hipStream_t stream) {
    const float* x      = (const float*)d_in[0];
    const float* conv_w = (const float*)d_in[1];
    const float* conv_b = (const float*)d_in[2];
    const float* coefs  = (const float*)d_in[3];
    float* out = (float*)d_out;

    const int blocks = BATCH * 4 /*o-groups*/ * 4 /*s-chunks*/ * NWIN;  // 8320
    trf_kernel<<<blocks, 256, 0, stream>>>(x, conv_w, conv_b, coefs, out);
}

// Round 11
// 95.738 us; speedup vs baseline: 1.2272x; 1.1970x over previous
//
#include <hip/hip_runtime.h>
#include <math.h>

#define BATCH 8
#define NSEQ  4096
#define NWIN  65
#define OUTD  64
#define NB    21

typedef __attribute__((ext_vector_type(4))) float f32x4;

// out[b,o,w,s] = a(b,s) * ( const0*coefs[o,0] + sum_{n=1..10} scale*(sin(n*th)*coefs[o,2n-1] + cos(n*th)*coefs[o,2n]) )
// th = (2*pi/78) * c(b,s) * ((w+7) - bshift(b,s))
// R6 structure (8320 blocks, og-fastest, NT store inside compute loop).
// Single change: 4 ROTATING accumulators instead of 16 dedicated -> VGPR
// ~120 < 128 cliff -> 4 waves/SIMD (was 3) for better store-stall hiding.
// Reuse distance 4 => vmcnt waits allow 12 outstanding stores (nearly free).
__global__ __launch_bounds__(256, 4) void trf_kernel(
    const float* __restrict__ x,        // (8,1,4096)
    const float* __restrict__ conv_w,   // (3,1,2)
    const float* __restrict__ conv_b,   // (3,)
    const float* __restrict__ coefs,    // (64,1,21)
    float* __restrict__ out)            // (8,64,65,4096)
{
    const int tid   = threadIdx.x;
    const int blk   = blockIdx.x;
    const int og    = blk & 3;           // output group: o = og*16 .. og*16+15
    const int chunk = (blk >> 2) & 3;    // 4 chunks of 1024 s each
    const int bw    = blk >> 4;
    const int w     = bw % NWIN;
    const int b     = bw / NWIN;
    const int s0    = chunk * 1024 + tid * 4;

    // conv weights: wave-uniform scalar loads
    const float w00 = conv_w[0], w01 = conv_w[1];
    const float w10 = conv_w[2], w11 = conv_w[3];
    const float w20 = conv_w[4], w21 = conv_w[5];
    const float cb0 = conv_b[0], cb1 = conv_b[1], cb2 = conv_b[2];

    const float* xb = x + (size_t)b * NSEQ;
    const f32x4 xq  = *(const f32x4*)(xb + s0);            // x[s0..s0+3], 16B aligned
    const float xm0 = (s0 > 0) ? xb[s0 - 1] : 0.0f;        // causal left-pad

    const float K      = 0.08055365778435367f;  // 2*pi/78
    const float SCALE  = 0.16012815380508713f;  // 1/sqrt(39)
    const float CONST0 = 0.11322770341445958f;  // 1/(sqrt(2)*sqrt(39))
    const float wl     = (float)(w + 7);

    f32x4 basis[NB];                                       // 84 VGPRs, static-indexed
#pragma unroll
    for (int p = 0; p < 4; ++p) {
        const float xm = (p == 0) ? xm0 : xq[p - 1];
        const float xc = xq[p];
        const float p0 = fmaf(xm, w00, fmaf(xc, w01, cb0));
        const float p1 = fmaf(xm, w10, fmaf(xc, w11, cb1));
        const float p2 = fmaf(xm, w20, fmaf(xc, w21, cb2));
        const float a  = fabsf(p0);
        const float bs = fminf(fmaxf(p1, -7.0f), 7.0f);
        const float c  = fminf(fmaxf(1.0f + p2, 0.5f), 1.4f);

        const float theta = K * c * (wl - bs);
        float sn, cn;
        __sincosf(theta, &sn, &cn);

        const float fa = a * SCALE;
        basis[0][p] = a * CONST0;
        const float twoc = 2.0f * cn;
        float sp = 0.0f, cp = 1.0f;      // sin(0), cos(0)
        float scur = sn, ccur = cn;      // sin(th), cos(th)
#pragma unroll
        for (int n = 1; n <= 10; ++n) {  // Chebyshev recurrence for sin/cos(n*th)
            basis[2 * n - 1][p] = fa * scur;
            basis[2 * n][p]     = fa * ccur;
            const float snew = fmaf(twoc, scur, -sp);
            const float cnew = fmaf(twoc, ccur, -cp);
            sp = scur; cp = ccur; scur = snew; ccur = cnew;
        }
    }

    // out index: ((b*64 + o)*65 + w)*4096 + s0
    float* op = out + ((size_t)(b * OUTD + og * 16) * NWIN + (size_t)w) * NSEQ + s0;
    const size_t ostride = (size_t)NWIN * NSEQ;

    const float* cwb = coefs + og * 16 * NB;   // uniform -> s_load batch
    f32x4 acc[4];                               // rotating accumulators
#pragma unroll
    for (int j = 0; j < 16; ++j) {
        const float* cw = cwb + j * NB;
        f32x4 a0 = basis[0] * cw[0];
#pragma unroll
        for (int n = 1; n < NB; ++n) {
            const float cs = cw[n];
            const f32x4 cv = {cs, cs, cs, cs};
            a0 = __builtin_elementwise_fma(basis[n], cv, a0);
        }
        acc[j & 3] = a0;
        // NT store issued inside compute loop (R6 pattern, measured best)
        __builtin_nontemporal_store(acc[j & 3], (f32x4*)(op + (size_t)j * ostride));
    }
}

extern "C" void kernel_launch(void* const* d_in, const int* in_sizes, int n_in,
                              void* d_out, int out_size, void* d_ws, size_t ws_size,
                              hipStream_t stream) {
    const float* x      = (const float*)d_in[0];
    const float* conv_w = (const float*)d_in[1];
    const float* conv_b = (const float*)d_in[2];
    const float* coefs  = (const float*)d_in[3];
    float* out = (float*)d_out;

    const int blocks = BATCH * NWIN * 4 /*s-chunks*/ * 4 /*o-groups*/;  // 8320
    trf_kernel<<<blocks, 256, 0, stream>>>(x, conv_w, conv_b, coefs, out);
}